// Round 11
// baseline (6876.151 us; speedup 1.0000x reference)
//
#include <hip/hip_runtime.h>
#include <hip/hip_bf16.h>

// Problem constants
#define BATCH   64
#define SEQ     512
#define DMODEL  256
#define HIDDEN  512
#define G3      1536      // 3*HIDDEN
#define NBLK    128       // scan blocks; 512 hidden units / 128 = 4 units/block
#define UPB     4         // units per block
#define CPB     12        // Wh columns per block (3 gates * UPB)
#define CHUNK   128       // timesteps per scan chunk-kernel
#define NCHUNK  4         // SEQ / CHUNK
#define HSLOTU  (HIDDEN * BATCH)   // u64 entries per h slot (256 KB)

typedef unsigned long long u64;
typedef unsigned int u32;

// ---------------------------------------------------------------------------
// Pack Wh slices: whp[blk][c][k] = Wh[k][ g*512 + blk*4 + u ]  (c = g*4+u)
// Contiguous in k -> wave-uniform weight reads scalarize (s_load, L2-hot).
// ---------------------------------------------------------------------------
__global__ __launch_bounds__(512) void prep_wh(const float* __restrict__ Wh,
                                               float* __restrict__ whp) {
    int t = blockIdx.x * 512 + threadIdx.x;      // 0 .. 786431
    int k   = t & 511;
    int cb  = t >> 9;          // blk*12 + c
    int c   = cb % 12;
    int blk = cb / 12;
    int u = c & 3, g = c >> 2;
    whp[t] = Wh[(long)k * G3 + g * HIDDEN + blk * UPB + u];
}

// ---------------------------------------------------------------------------
// Chunked xg GEMM: xgC[col][lt][b] = emb[ids[b][s]] . Wx[:,col] + bx[col],
// s = chunk*CHUNK + lt. One buffer reused per chunk; the consumer scan is a
// later kernel launch (entry-acquire) so reuse is coherent.
// ---------------------------------------------------------------------------
__global__ __launch_bounds__(256) void xg_gemm(const int* __restrict__ ids,
                                               const float* __restrict__ emb,
                                               const float* __restrict__ Wx,
                                               const float* __restrict__ bx,
                                               float* __restrict__ xgC,
                                               int chunk) {
    __shared__ float Es[64][68];   // Es[k][b], padded
    __shared__ float Ws[64][68];   // Ws[k][c], padded
    __shared__ int   sids[64];

    const int tid = threadIdx.x;
    const int nb = blockIdx.x;     // col tile 0..23
    const int lt = blockIdx.y;     // local timestep 0..127
    const int s  = chunk * CHUNK + lt;
    const int tn = tid & 15;
    const int tm = tid >> 4;

    if (tid < 64) sids[tid] = ids[tid * SEQ + s];   // id for batch=tid, step s
    __syncthreads();

    float acc[4][4];               // acc[i=col][j=b]
#pragma unroll
    for (int i = 0; i < 4; ++i)
#pragma unroll
        for (int j = 0; j < 4; ++j) acc[i][j] = 0.f;

    for (int kb = 0; kb < 256; kb += 64) {
#pragma unroll
        for (int p = 0; p < 4; ++p) {
            int b = p * 16 + tm;
            float4 av = *(const float4*)(emb + (long)sids[b] * DMODEL + kb + tn * 4);
            Es[tn * 4 + 0][b] = av.x;
            Es[tn * 4 + 1][b] = av.y;
            Es[tn * 4 + 2][b] = av.z;
            Es[tn * 4 + 3][b] = av.w;
            int krow = p * 16 + tm;
            float4 wv = *(const float4*)(Wx + (long)(kb + krow) * G3 + nb * 64 + tn * 4);
            *(float4*)&Ws[krow][tn * 4] = wv;
        }
        __syncthreads();
#pragma unroll
        for (int k = 0; k < 64; ++k) {
            float4 w4 = *(const float4*)&Ws[k][tm * 4];
            float4 e4 = *(const float4*)&Es[k][tn * 4];
            float ww[4] = {w4.x, w4.y, w4.z, w4.w};
            float ee[4] = {e4.x, e4.y, e4.z, e4.w};
#pragma unroll
            for (int i = 0; i < 4; ++i)
#pragma unroll
                for (int j = 0; j < 4; ++j)
                    acc[i][j] = fmaf(ww[i], ee[j], acc[i][j]);
        }
        __syncthreads();
    }

#pragma unroll
    for (int i = 0; i < 4; ++i) {
        int col = nb * 64 + tm * 4 + i;
        float bxi = bx[col];
        float4 o;
        o.x = acc[i][0] + bxi;
        o.y = acc[i][1] + bxi;
        o.z = acc[i][2] + bxi;
        o.w = acc[i][3] + bxi;
        *(float4*)(xgC + (long)col * (CHUNK * BATCH) + lt * 64 + tn * 4) = o;
    }
}

// ---------------------------------------------------------------------------
// GRU scan v11: DATAFLOW handshake — the data is the flag. No barrier.
// R4-R10 showed ~10us/step is invariant under every h-load style: the cost
// is the lockstep barrier chain (drain + flag RTT + 128-way poll + per-step
// max-of-jitter). Here h entries are (tag=t)<<32|fp32 u64 pairs in R8's
// rotating fresh slots. Consumers bulk-load 32 x dwordx4 (asm-pinned, one
// waitcnt), then retry ONLY stale-tagged entries with L2-bypassing atomic
// loads + s_sleep backoff. Blocks slip freely — jitter pipelines away
// instead of accumulating as a per-step max.
// Why this is safe where v6 wasn't: fresh slots mean a plain load can only
// lose a race in TIME (tag catches it, atomic retry bypasses the cache);
// there is never a resident stale line for this slot from earlier use.
// ABA (v3 argument): slot lt is rewritten (tag t+128) only after its writer
// consumed tag t+127 from ALL blocks, transitively after every block
// consumed tag t -> exact tag==t check is sound. Chunk boundaries are
// kernel boundaries (entry acquire / stream order).
// Producer stores are agent-scope relaxed atomics = write-through to the
// coherence point (the property that made v2-v10 correct).
// ---------------------------------------------------------------------------
__global__ __launch_bounds__(512, 2) void gru_scan(const float* __restrict__ whp,
                                                   const float* __restrict__ xgC,
                                                   const float* __restrict__ bh,
                                                   u64* hist,
                                                   int chunk) {
    const int tid = threadIdx.x;
    const int blk = blockIdx.x;
    const int b   = tid & 63;                                 // lane = batch
    const int wu  = __builtin_amdgcn_readfirstlane(tid >> 6); // wave 0..7

    __shared__ float part[8][CPB][64];   // 24 KB partial sums
    __shared__ float hl[UPB][64];        // this block's own h slice

    const float* wb = whp + blk * (CPB * HIDDEN) + wu * 64;   // + c*512 + k
    const int base = chunk * CHUNK;

    const int gu = tid >> 6;
    int jg = 0;
    float bhr = 0.f, bhz = 0.f, bhn = 0.f;
    const float* xr_p = nullptr; const float* xz_p = nullptr; const float* xn_p = nullptr;
    if (tid < 256) {
        jg  = blk * UPB + gu;
        bhr = bh[jg];
        bhz = bh[HIDDEN + jg];
        bhn = bh[2 * HIDDEN + jg];
        xr_p = xgC + (long)jg * (CHUNK * BATCH) + b;
        xz_p = xgC + (long)(HIDDEN + jg) * (CHUNK * BATCH) + b;
        xn_p = xgC + (long)(2 * HIDDEN + jg) * (CHUNK * BATCH) + b;
        // slot 0 holds h[base] (written by previous chunk kernel; fresh via
        // kernel-entry acquire). Value = low 32 bits of the unit's u64.
        // unit jg -> u64 index ((jg>>1)*64 + b)*2 + (jg&1)
        hl[gu][b] = (chunk == 0)
            ? 0.f
            : __uint_as_float((u32)hist[((long)(2 * blk + (gu >> 1)) * 64 + b) * 2
                                        + (gu & 1)]);
    }
    __syncthreads();

#pragma unroll 1
    for (int lt = 0; lt < CHUNK; ++lt) {
        const int t = base + lt;
        u64* slot  = hist + (long)lt * HSLOTU;                       // h[t]
        u64* slotn = hist + (long)((lt + 1) & (CHUNK - 1)) * HSLOTU; // h[t+1]

        // gate inputs: plain cached loads (xgC stays L2-hot)
        float xr = 0.f, xz = 0.f, xn = 0.f, hprev = 0.f;
        if (tid < 256) {
            xr = xr_p[lt * 64];
            xz = xz_p[lt * 64];
            xn = xn_p[lt * 64];
            hprev = hl[gu][b];
        }

        if (t > 0) {
            // bulk read of h[t]: wave wu owns pairs [wu*32, wu*32+32), each
            // pair = 16B = 2 units (val,tag | val,tag). Pinned issue order.
            const float4* hs4 = (const float4*)slot;
            const u32 want = (u32)t;
            float4 hv[32];
#pragma unroll
            for (int i = 0; i < 32; ++i)
                asm volatile("global_load_dwordx4 %0, %1, off"
                             : "=v"(hv[i])
                             : "v"(hs4 + (long)(wu * 32 + i) * 64 + b)
                             : "memory");
            asm volatile("s_waitcnt vmcnt(0)" ::: "memory");

            u64 v[64];
#pragma unroll
            for (int i = 0; i < 32; ++i) {
                v[2 * i]     = ((u64)__float_as_uint(hv[i].y) << 32)
                             | (u64)__float_as_uint(hv[i].x);
                v[2 * i + 1] = ((u64)__float_as_uint(hv[i].w) << 32)
                             | (u64)__float_as_uint(hv[i].z);
            }
            // dataflow wait: retry ONLY stale entries at the coherence point
            for (;;) {
                bool ok = true;
#pragma unroll
                for (int k = 0; k < 64; ++k) {
                    if ((u32)(v[k] >> 32) != want) {
                        ok = false;
                        const long p = (long)(wu * 32) + (k >> 1);
                        v[k] = __hip_atomic_load(slot + (p * 64 + b) * 2 + (k & 1),
                                                 __ATOMIC_RELAXED,
                                                 __HIP_MEMORY_SCOPE_AGENT);
                    }
                }
                if (__all(ok)) break;
                __builtin_amdgcn_s_sleep(1);
            }

            float acc[CPB];
#pragma unroll
            for (int c = 0; c < CPB; ++c) acc[c] = 0.f;
#pragma unroll
            for (int k = 0; k < 64; ++k) {
                const float hvv = __uint_as_float((u32)v[k]);
#pragma unroll
                for (int c = 0; c < CPB; ++c)
                    acc[c] = fmaf(hvv, wb[c * HIDDEN + k], acc[c]);
            }
#pragma unroll
            for (int c = 0; c < CPB; ++c) part[wu][c][b] = acc[c];
        } else {
            // h0 == 0 => hg = bh
#pragma unroll
            for (int c = 0; c < CPB; ++c) part[wu][c][b] = 0.f;
        }
        __syncthreads();                               // A: partials ready

        if (tid < 256) {
            float hgr = bhr, hgz = bhz, hgn = bhn;
#pragma unroll
            for (int ww = 0; ww < 8; ++ww) {
                hgr += part[ww][gu][b];
                hgz += part[ww][4 + gu][b];
                hgn += part[ww][8 + gu][b];
            }
            float r  = 1.f / (1.f + expf(-(xr + hgr)));
            float z  = 1.f / (1.f + expf(-(xz + hgz)));
            float nn = tanhf(xn + r * hgn);
            hl[gu][b] = (1.f - z) * nn + z * hprev;
        }
        __syncthreads();                               // B: hl ready

        // producers: publish tagged h[t+1]; no drain, no flag, no barrier.
        if (tid < 128) {
            const int p = tid >> 6;                    // unit pair 0..1
            const u32 tg = (u32)(t + 1);
            u64* dst = slotn + ((long)(2 * blk + p) * 64 + b) * 2;
            u64 pk0 = ((u64)tg << 32) | (u64)__float_as_uint(hl[2 * p][b]);
            u64 pk1 = ((u64)tg << 32) | (u64)__float_as_uint(hl[2 * p + 1][b]);
            __hip_atomic_store(dst + 0, pk0, __ATOMIC_RELAXED,
                               __HIP_MEMORY_SCOPE_AGENT);
            __hip_atomic_store(dst + 1, pk1, __ATOMIC_RELAXED,
                               __HIP_MEMORY_SCOPE_AGENT);
        }
        // loop: next iteration's consumer spin provides the ordering.
    }
}

// ---------------------------------------------------------------------------
// head: logits[b][n] = sum_k h[k][b] * Wo[k][n] + bo[n]
// h[512] sits in hist slot 0 (tag 512), value = low 32 bits of each u64.
// ---------------------------------------------------------------------------
__global__ void head_kernel(const u64* __restrict__ hist,
                            const float* __restrict__ Wo,
                            const float* __restrict__ bo,
                            float* __restrict__ out) {
    int tid = threadIdx.x;        // 128 threads
    int b = tid >> 1, n = tid & 1;
    float acc = bo[n];
#pragma unroll 8
    for (int k = 0; k < HIDDEN; ++k) {
        u64 e = hist[((long)(k >> 1) * 64 + b) * 2 + (k & 1)];
        acc = fmaf(__uint_as_float((u32)e), Wo[k * 2 + n], acc);
    }
    out[b * 2 + n] = acc;
}

// ---------------------------------------------------------------------------
extern "C" void kernel_launch(void* const* d_in, const int* in_sizes, int n_in,
                              void* d_out, int out_size, void* d_ws, size_t ws_size,
                              hipStream_t stream) {
    (void)in_sizes; (void)n_in; (void)out_size; (void)ws_size;
    const int*   ids = (const int*)  d_in[0];
    const float* emb = (const float*)d_in[1];
    const float* Wx  = (const float*)d_in[2];
    const float* Wh  = (const float*)d_in[3];
    const float* bx  = (const float*)d_in[4];
    const float* bh  = (const float*)d_in[5];
    const float* Wo  = (const float*)d_in[6];
    const float* bo  = (const float*)d_in[7];
    float* out = (float*)d_out;

    char* ws = (char*)d_ws;
    // ws layout: [hist 32MB (128 slots x 256KB, tagged u64)][whp 3MB][xgC 50.3MB]
    // hist needs NO init: poison 0xAAAAAAAA never equals a tag in [1,512],
    // and chunk0/lt0 skips the read analytically (h0=0).
    u64*   hist = (u64*)ws;
    float* whp  = (float*)(ws + (size_t)CHUNK * HSLOTU * sizeof(u64));
    float* xgC  = (float*)(ws + (size_t)CHUNK * HSLOTU * sizeof(u64)
                           + (size_t)NBLK * CPB * HIDDEN * 4);

    prep_wh<<<dim3(1536), dim3(512), 0, stream>>>(Wh, whp);
    for (int c = 0; c < NCHUNK; ++c) {
        xg_gemm<<<dim3(24, CHUNK), dim3(256), 0, stream>>>(ids, emb, Wx, bx, xgC, c);
        gru_scan<<<dim3(NBLK), dim3(512), 0, stream>>>(whp, xgC, bh, hist, c);
    }
    head_kernel<<<dim3(1), dim3(128), 0, stream>>>(hist, Wo, bo, out);
}

// Round 12
// 6065.469 us; speedup vs baseline: 1.1337x; 1.1337x over previous
//
#include <hip/hip_runtime.h>
#include <hip/hip_bf16.h>

// Problem constants
#define BATCH   64
#define SEQ     512
#define DMODEL  256
#define HIDDEN  512
#define G3      1536      // 3*HIDDEN
#define NBLK    128       // scan blocks; 512 hidden units / 128 = 4 units/block
#define UPB     4         // units per block
#define CPB     12        // Wh columns per block (3 gates * UPB)
#define CHUNK   128       // timesteps per scan chunk-kernel
#define NCHUNK  4         // SEQ / CHUNK
#define HSLOTU  (HIDDEN * BATCH)   // u64 entries per h slot (256 KB)

typedef unsigned long long u64;
typedef unsigned int u32;

// ---------------------------------------------------------------------------
// Pack Wh slices: whp[blk][c][k] = Wh[k][ g*512 + blk*4 + u ]  (c = g*4+u)
// Contiguous in k -> wave-uniform weight reads scalarize (s_load, L2-hot).
// ---------------------------------------------------------------------------
__global__ __launch_bounds__(512) void prep_wh(const float* __restrict__ Wh,
                                               float* __restrict__ whp) {
    int t = blockIdx.x * 512 + threadIdx.x;      // 0 .. 786431
    int k   = t & 511;
    int cb  = t >> 9;          // blk*12 + c
    int c   = cb % 12;
    int blk = cb / 12;
    int u = c & 3, g = c >> 2;
    whp[t] = Wh[(long)k * G3 + g * HIDDEN + blk * UPB + u];
}

// ---------------------------------------------------------------------------
// Chunked xg GEMM: xgC[col][lt][b] = emb[ids[b][s]] . Wx[:,col] + bx[col],
// s = chunk*CHUNK + lt. One buffer reused per chunk; the consumer scan is a
// later kernel launch (entry-acquire) so reuse is coherent.
// ---------------------------------------------------------------------------
__global__ __launch_bounds__(256) void xg_gemm(const int* __restrict__ ids,
                                               const float* __restrict__ emb,
                                               const float* __restrict__ Wx,
                                               const float* __restrict__ bx,
                                               float* __restrict__ xgC,
                                               int chunk) {
    __shared__ float Es[64][68];   // Es[k][b], padded
    __shared__ float Ws[64][68];   // Ws[k][c], padded
    __shared__ int   sids[64];

    const int tid = threadIdx.x;
    const int nb = blockIdx.x;     // col tile 0..23
    const int lt = blockIdx.y;     // local timestep 0..127
    const int s  = chunk * CHUNK + lt;
    const int tn = tid & 15;
    const int tm = tid >> 4;

    if (tid < 64) sids[tid] = ids[tid * SEQ + s];   // id for batch=tid, step s
    __syncthreads();

    float acc[4][4];               // acc[i=col][j=b]
#pragma unroll
    for (int i = 0; i < 4; ++i)
#pragma unroll
        for (int j = 0; j < 4; ++j) acc[i][j] = 0.f;

    for (int kb = 0; kb < 256; kb += 64) {
#pragma unroll
        for (int p = 0; p < 4; ++p) {
            int b = p * 16 + tm;
            float4 av = *(const float4*)(emb + (long)sids[b] * DMODEL + kb + tn * 4);
            Es[tn * 4 + 0][b] = av.x;
            Es[tn * 4 + 1][b] = av.y;
            Es[tn * 4 + 2][b] = av.z;
            Es[tn * 4 + 3][b] = av.w;
            int krow = p * 16 + tm;
            float4 wv = *(const float4*)(Wx + (long)(kb + krow) * G3 + nb * 64 + tn * 4);
            *(float4*)&Ws[krow][tn * 4] = wv;
        }
        __syncthreads();
#pragma unroll
        for (int k = 0; k < 64; ++k) {
            float4 w4 = *(const float4*)&Ws[k][tm * 4];
            float4 e4 = *(const float4*)&Es[k][tn * 4];
            float ww[4] = {w4.x, w4.y, w4.z, w4.w};
            float ee[4] = {e4.x, e4.y, e4.z, e4.w};
#pragma unroll
            for (int i = 0; i < 4; ++i)
#pragma unroll
                for (int j = 0; j < 4; ++j)
                    acc[i][j] = fmaf(ww[i], ee[j], acc[i][j]);
        }
        __syncthreads();
    }

#pragma unroll
    for (int i = 0; i < 4; ++i) {
        int col = nb * 64 + tm * 4 + i;
        float bxi = bx[col];
        float4 o;
        o.x = acc[i][0] + bxi;
        o.y = acc[i][1] + bxi;
        o.z = acc[i][2] + bxi;
        o.w = acc[i][3] + bxi;
        *(float4*)(xgC + (long)col * (CHUNK * BATCH) + lt * 64 + tn * 4) = o;
    }
}

// ---------------------------------------------------------------------------
// GRU scan v12: dataflow tagged h (v11) + WIDE COHERENT (sc0 sc1) asm loads.
// Session law (v2-v11): every coherent load flavor the compiler emits
// (atomic, volatile) is issued one-per-waitcnt -> any coherent read of h
// costs a 30-60 deep latency chain = the ~10us/step plateau. But the ISA
// allows wide coherent issue: global_load_dwordx4 with sc0 sc1 bypasses
// L1/L2 (reads the coherence point) and is an ordinary vmcnt op. Inline asm
// issues 32 of them back-to-back with ONE s_waitcnt -> ~1 RTT per pass.
// The tag check (entries carry tag=t) decides whether to re-pass (with
// s_sleep backoff). No flags, no barrier, no drain: blocks slip freely.
// Also: producers store tagged h directly from gate threads (h_prev lives
// in a register, not LDS), and part[] is double-buffered -> exactly ONE
// __syncthreads per step.
// ABA-safe (v3 argument, 128-slot rotation); chunk boundaries are kernel
// boundaries. Deadlock-free: producers never wait on consumers.
// ---------------------------------------------------------------------------
__global__ __launch_bounds__(512, 2) void gru_scan(const float* __restrict__ whp,
                                                   const float* __restrict__ xgC,
                                                   const float* __restrict__ bh,
                                                   u64* hist,
                                                   int chunk) {
    const int tid = threadIdx.x;
    const int blk = blockIdx.x;
    const int b   = tid & 63;                                 // lane = batch
    const int wu  = __builtin_amdgcn_readfirstlane(tid >> 6); // wave 0..7

    __shared__ float part[2][8][CPB][64];   // 48 KB, double-buffered

    const float* wb = whp + blk * (CPB * HIDDEN) + wu * 64;   // + c*512 + k
    const int base = chunk * CHUNK;

    const int gu = tid >> 6;
    int jg = 0;
    float bhr = 0.f, bhz = 0.f, bhn = 0.f, hprev = 0.f;
    const float* xr_p = nullptr; const float* xz_p = nullptr; const float* xn_p = nullptr;
    u64* gdst_base = nullptr;
    if (tid < 256) {
        jg  = blk * UPB + gu;
        bhr = bh[jg];
        bhz = bh[HIDDEN + jg];
        bhn = bh[2 * HIDDEN + jg];
        xr_p = xgC + (long)jg * (CHUNK * BATCH) + b;
        xz_p = xgC + (long)(HIDDEN + jg) * (CHUNK * BATCH) + b;
        xn_p = xgC + (long)(2 * HIDDEN + jg) * (CHUNK * BATCH) + b;
        // unit jg -> u64 index ((jg>>1)*64 + b)*2 + (jg&1); pair q=2blk+(gu>>1)
        gdst_base = hist + ((long)(2 * blk + (gu >> 1)) * 64 + b) * 2 + (gu & 1);
        // h[base]: slot 0, written by previous chunk kernel (or h0=0)
        hprev = (chunk == 0)
            ? 0.f
            : __uint_as_float((u32)hist[((long)(2 * blk + (gu >> 1)) * 64 + b) * 2
                                        + (gu & 1)]);
    }
    __syncthreads();

#pragma unroll 1
    for (int lt = 0; lt < CHUNK; ++lt) {
        const int t = base + lt;
        const int pb = lt & 1;
        const u64* slot  = hist + (long)lt * HSLOTU;                       // h[t]
        u64*       slotn = hist + (long)((lt + 1) & (CHUNK - 1)) * HSLOTU; // h[t+1]

        // gate inputs: plain cached loads (xgC stays L2-hot)
        float xr = 0.f, xz = 0.f, xn = 0.f;
        if (tid < 256) {
            xr = xr_p[lt * 64];
            xz = xz_p[lt * 64];
            xn = xn_p[lt * 64];
        }

        if (t > 0) {
            // WIDE COHERENT read of h[t]: 32 x global_load_dwordx4 sc0 sc1
            // (L1/L2 bypass), one waitcnt. Re-pass until all tags == t.
            // float4 = (val0,tag0,val1,tag1) for units 2q, 2q+1, q=wu*32+i.
            const float4* hs4 = (const float4*)slot;
            const u32 want = (u32)t;
            float4 hv[32];
            bool first = true;
            for (;;) {
                if (!first) __builtin_amdgcn_s_sleep(1);
                first = false;
#pragma unroll
                for (int i = 0; i < 32; ++i)
                    asm volatile("global_load_dwordx4 %0, %1, off sc0 sc1"
                                 : "=v"(hv[i])
                                 : "v"(hs4 + (long)(wu * 32 + i) * 64 + b)
                                 : "memory");
                asm volatile("s_waitcnt vmcnt(0)" ::: "memory");
                bool ok = true;
#pragma unroll
                for (int i = 0; i < 32; ++i)
                    ok = ok && (__float_as_uint(hv[i].y) == want)
                            && (__float_as_uint(hv[i].w) == want);
                if (__all(ok)) break;
            }

            float acc[CPB];
#pragma unroll
            for (int c = 0; c < CPB; ++c) acc[c] = 0.f;
#pragma unroll
            for (int i = 0; i < 32; ++i) {
                const int k0 = 2 * i, k1 = 2 * i + 1;
                const float h0 = hv[i].x, h1 = hv[i].z;
#pragma unroll
                for (int c = 0; c < CPB; ++c) {
                    acc[c] = fmaf(h0, wb[c * HIDDEN + k0], acc[c]);
                    acc[c] = fmaf(h1, wb[c * HIDDEN + k1], acc[c]);
                }
            }
#pragma unroll
            for (int c = 0; c < CPB; ++c) part[pb][wu][c][b] = acc[c];
        } else {
            // h0 == 0 => hg = bh
#pragma unroll
            for (int c = 0; c < CPB; ++c) part[pb][wu][c][b] = 0.f;
        }
        __syncthreads();                    // the ONLY barrier per step

        if (tid < 256) {
            float hgr = bhr, hgz = bhz, hgn = bhn;
#pragma unroll
            for (int ww = 0; ww < 8; ++ww) {
                hgr += part[pb][ww][gu][b];
                hgz += part[pb][ww][4 + gu][b];
                hgn += part[pb][ww][8 + gu][b];
            }
            float r  = 1.f / (1.f + expf(-(xr + hgr)));
            float z  = 1.f / (1.f + expf(-(xz + hgz)));
            float nn = tanhf(xn + r * hgn);
            float hnew = (1.f - z) * nn + z * hprev;
            hprev = hnew;
            // publish tagged h[t+1] immediately (agent write-through)
            u64 pk = ((u64)(u32)(t + 1) << 32) | (u64)__float_as_uint(hnew);
            __hip_atomic_store(slotn + (gdst_base - hist), pk,
                               __ATOMIC_RELAXED, __HIP_MEMORY_SCOPE_AGENT);
        }
        // no second barrier: next step's matvec uses part[1-pb]; its writes
        // cannot race this step's part[pb] reads (those complete before the
        // reader passes the next __syncthreads).
    }
}

// ---------------------------------------------------------------------------
// head: logits[b][n] = sum_k h[k][b] * Wo[k][n] + bo[n]
// h[512] sits in hist slot 0 (tag 512), value = low 32 bits of each u64.
// ---------------------------------------------------------------------------
__global__ void head_kernel(const u64* __restrict__ hist,
                            const float* __restrict__ Wo,
                            const float* __restrict__ bo,
                            float* __restrict__ out) {
    int tid = threadIdx.x;        // 128 threads
    int b = tid >> 1, n = tid & 1;
    float acc = bo[n];
#pragma unroll 8
    for (int k = 0; k < HIDDEN; ++k) {
        u64 e = hist[((long)(k >> 1) * 64 + b) * 2 + (k & 1)];
        acc = fmaf(__uint_as_float((u32)e), Wo[k * 2 + n], acc);
    }
    out[b * 2 + n] = acc;
}

// ---------------------------------------------------------------------------
extern "C" void kernel_launch(void* const* d_in, const int* in_sizes, int n_in,
                              void* d_out, int out_size, void* d_ws, size_t ws_size,
                              hipStream_t stream) {
    (void)in_sizes; (void)n_in; (void)out_size; (void)ws_size;
    const int*   ids = (const int*)  d_in[0];
    const float* emb = (const float*)d_in[1];
    const float* Wx  = (const float*)d_in[2];
    const float* Wh  = (const float*)d_in[3];
    const float* bx  = (const float*)d_in[4];
    const float* bh  = (const float*)d_in[5];
    const float* Wo  = (const float*)d_in[6];
    const float* bo  = (const float*)d_in[7];
    float* out = (float*)d_out;

    char* ws = (char*)d_ws;
    // ws layout: [hist 32MB (128 slots x 256KB, tagged u64)][whp 3MB][xgC 50.3MB]
    // hist needs NO init: poison 0xAAAAAAAA never equals a tag in [1,512],
    // and chunk0/lt0 skips the read analytically (h0=0).
    u64*   hist = (u64*)ws;
    float* whp  = (float*)(ws + (size_t)CHUNK * HSLOTU * sizeof(u64));
    float* xgC  = (float*)(ws + (size_t)CHUNK * HSLOTU * sizeof(u64)
                           + (size_t)NBLK * CPB * HIDDEN * 4);

    prep_wh<<<dim3(1536), dim3(512), 0, stream>>>(Wh, whp);
    for (int c = 0; c < NCHUNK; ++c) {
        xg_gemm<<<dim3(24, CHUNK), dim3(256), 0, stream>>>(ids, emb, Wx, bx, xgC, c);
        gru_scan<<<dim3(NBLK), dim3(512), 0, stream>>>(whp, xgC, bh, hist, c);
    }
    head_kernel<<<dim3(1), dim3(128), 0, stream>>>(hist, Wo, bo, out);
}